// Round 6
// baseline (2042.446 us; speedup 1.0000x reference)
//
#include <hip/hip_runtime.h>
#include <hip/hip_bf16.h>
#include <stdint.h>

// Problem constants (from reference)
#define NN 20000     // nodes
#define NE 320000    // edges
#define HH 256       // hidden
#define EDK 64       // edge_dim
#define NSTEPS 4
#define ECH 160000   // edges per chunk (Pe buffer covers one chunk)
#define WSTEP 606208 // bf16 elems of transposed weights per step

typedef __attribute__((ext_vector_type(8))) short bf16x8;
typedef __attribute__((ext_vector_type(4))) float f32x4;

__device__ __forceinline__ float silu_f(float x) { return x / (1.0f + __expf(-x)); }

__device__ __forceinline__ unsigned short f2bf(float f) {
    __hip_bfloat16 h = __float2bfloat16(f);
    return __builtin_bit_cast(unsigned short, h);
}
__device__ __forceinline__ float bf2f(unsigned short u) {
    unsigned int x = ((unsigned int)u) << 16;
    return __builtin_bit_cast(float, x);
}

// ---------------- LayerNorm: fp32 in, bf16 out; one wave per row of 256 ----------------
__global__ void ln_kernel(const float* __restrict__ x, const float* __restrict__ g,
                          const float* __restrict__ b, unsigned short* __restrict__ y, int M)
{
    int row  = blockIdx.x * 4 + (threadIdx.x >> 6);
    int lane = threadIdx.x & 63;
    if (row >= M) return;
    float4 v = *(const float4*)(x + (size_t)row * HH + lane * 4);
    float s  = v.x + v.y + v.z + v.w;
    float ss = v.x*v.x + v.y*v.y + v.z*v.z + v.w*v.w;
#pragma unroll
    for (int off = 32; off > 0; off >>= 1) {
        s  += __shfl_down(s, off);
        ss += __shfl_down(ss, off);
    }
    float mean = __shfl(s, 0) * (1.0f / HH);
    float ms   = __shfl(ss, 0) * (1.0f / HH);
    float rstd = rsqrtf(ms - mean * mean + 1e-5f);
    float4 gg = *(const float4*)(g + lane * 4);
    float4 bb = *(const float4*)(b + lane * 4);
    ushort4 o;
    o.x = f2bf((v.x - mean) * rstd * gg.x + bb.x);
    o.y = f2bf((v.y - mean) * rstd * gg.y + bb.y);
    o.z = f2bf((v.z - mean) * rstd * gg.z + bb.z);
    o.w = f2bf((v.w - mean) * rstd * gg.w + bb.w);
    *(ushort4*)(y + (size_t)row * HH + lane * 4) = o;
}

// ---------------- weight transpose + bf16 convert: all 24 matrices, one launch ----------------
__global__ void wtr_kernel(const float* __restrict__ eW1, const float* __restrict__ eW2,
                           const float* __restrict__ nW1, const float* __restrict__ nW2,
                           unsigned short* __restrict__ wbuf)
{
    int bx = blockIdx.x;
    int s  = bx / 592, t = bx % 592;
    const float* e1 = eW1 + (size_t)s * 576 * 256;
    unsigned short* wb = wbuf + (size_t)s * WSTEP;
    const float* src; unsigned short* dst; int K, N;
    if      (t < 64)  { src = e1;                          K = 256; N = 256; dst = wb; }
    else if (t < 128) { src = e1 + 65536;                  K = 256; N = 256; dst = wb + 65536;  t -= 64; }
    else if (t < 144) { src = e1 + 131072;                 K = 64;  N = 256; dst = wb + 131072; t -= 128; }
    else if (t < 208) { src = eW2 + (size_t)s * 65536;     K = 256; N = 256; dst = wb + 147456; t -= 144; }
    else if (t < 464) { src = nW1 + (size_t)s * 262144;    K = 512; N = 512; dst = wb + 212992; t -= 208; }
    else              { src = nW2 + (size_t)s * 131072;    K = 512; N = 256; dst = wb + 475136; t -= 464; }
    int ntn = N >> 5;
    int tk = t / ntn, tn = t % ntn;
    int k0 = tk * 32, n0 = tn * 32;
    __shared__ float ts[32][33];
    int tx = threadIdx.x & 31, ty = threadIdx.x >> 5;
#pragma unroll
    for (int i = 0; i < 4; i++)
        ts[ty + i * 8][tx] = src[(size_t)(k0 + ty + i * 8) * N + n0 + tx];
    __syncthreads();
#pragma unroll
    for (int i = 0; i < 4; i++)
        dst[(size_t)(n0 + ty + i * 8) * K + k0 + tx] = f2bf(ts[tx][ty + i * 8]);
}

// ---------------- edge_attr gather-to-sorted-order + bf16 convert (once per launch) ----------------
__global__ void easort_kernel(const float* __restrict__ ea, const int* __restrict__ eorig,
                              unsigned short* __restrict__ out)
{
    int gid = blockIdx.x * 256 + threadIdx.x;
    int p = gid >> 4, q = gid & 15;
    if (p >= NE) return;
    float4 v = *(const float4*)(ea + (size_t)eorig[p] * EDK + q * 4);
    ushort4 o;
    o.x = f2bf(v.x); o.y = f2bf(v.y); o.z = f2bf(v.z); o.w = f2bf(v.w);
    *(ushort4*)(out + (size_t)p * EDK + q * 4) = o;
}

// ---------------- MFMA bf16 GEMM, software-pipelined (register prefetch) ----------------
// C[M,Nc] = A[M,K] @ BT[Nc,K]^T (+epilogue)
// EPI: 0 = acc+bias   1 = silu(acc+bias)   2 = (acc + cnt*bias)/max(cnt,1)   3 = C += acc+bias
// ASRC: 3 = bf16 rows (lda)   4 = concat bf16 A|A2 (ld 256 each)
// TM: M-tiles processed per block (flat (mt,ki) pipeline; prefetch spans tile boundaries)
#define GBM 128
#define GBN 128
#define GBK 64
template <int EPI, int ASRC, bool BF16OUT, int TM>
__global__ __launch_bounds__(256) void mgemm(
    const void* __restrict__ A, const void* __restrict__ A2, int lda,
    const unsigned short* __restrict__ BT,
    const float* __restrict__ bias, const int* __restrict__ cnt,
    void* __restrict__ Cout, int M, int Nc, int K)
{
    __shared__ unsigned short smem[GBM * GBK + GBN * GBK];  // 32 KB; reused by bf16 epilogue
    unsigned short* lsA = smem;
    unsigned short* lsB = smem + GBM * GBK;
    const int tid = threadIdx.x;
    const int col0 = blockIdx.y * GBN;
    const int r = tid >> 1, half = tid & 1;      // staging row / half-row
    const int w = tid >> 6, l = tid & 63;        // wave id / lane
    const int wm = w >> 1, wn = w & 1;           // 2x2 wave grid, 64x64 per wave
    const int bx0 = blockIdx.x * TM;

    const unsigned short* Ab  = (const unsigned short*)A;
    const unsigned short* A2b = (const unsigned short*)A2;
    const unsigned short* brow = BT + (size_t)(col0 + r) * K;

    const int KI = K >> 6;          // K / GBK
    const int NIT = TM * KI;

    uint4 cA[4], cB[4], nA[4], nB[4];

    auto loadAB = [&](int mt2, int k0, uint4* dA, uint4* dB) {
        int grow = (bx0 + mt2) * GBM + r;
        if (grow < M) {
            const unsigned short* ap;
            if constexpr (ASRC == 4)
                ap = ((k0 < 256) ? Ab : A2b) + (size_t)grow * 256 + (k0 & 255) + half * 32;
            else
                ap = Ab + (size_t)grow * lda + k0 + half * 32;
#pragma unroll
            for (int ci = 0; ci < 4; ci++) dA[ci] = ((const uint4*)ap)[ci];
        } else {
#pragma unroll
            for (int ci = 0; ci < 4; ci++) dA[ci] = make_uint4(0, 0, 0, 0);
        }
        const unsigned short* bp = brow + k0 + half * 32;
#pragma unroll
        for (int ci = 0; ci < 4; ci++) dB[ci] = ((const uint4*)bp)[ci];
    };

    f32x4 acc[4][4] = {};
    loadAB(0, 0, cA, cB);

    int mt = 0, ki = 0;
    for (int it = 0; it < NIT; ++it) {
        // ---- stage current regs -> LDS (16B-chunk XOR swizzle) ----
#pragma unroll
        for (int ci = 0; ci < 4; ci++) {
            int slot = half * 4 + ci;
            int phys = slot ^ (r & 7);
            *(uint4*)&lsA[r * GBK + phys * 8] = cA[ci];
            *(uint4*)&lsB[r * GBK + phys * 8] = cB[ci];
        }
        __syncthreads();
        // ---- issue next tile's global loads (overlap with MFMA below) ----
        int nki = ki + 1, nmt = mt;
        if (nki == KI) { nki = 0; ++nmt; }
        if (nmt < TM) loadAB(nmt, nki << 6, nA, nB);
        // ---- 2 k-steps of 16x16x32 MFMAs ----
#pragma unroll
        for (int ks = 0; ks < 2; ks++) {
            bf16x8 bfr[4];
#pragma unroll
            for (int n = 0; n < 4; n++) {
                int rn = wn * 64 + n * 16 + (l & 15);
                int phys = (ks * 4 + (l >> 4)) ^ (rn & 7);
                bfr[n] = *(bf16x8*)&lsB[rn * GBK + phys * 8];
            }
#pragma unroll
            for (int m = 0; m < 4; m++) {
                int rm = wm * 64 + m * 16 + (l & 15);
                int phys = (ks * 4 + (l >> 4)) ^ (rm & 7);
                bf16x8 af = *(bf16x8*)&lsA[rm * GBK + phys * 8];
#pragma unroll
                for (int n = 0; n < 4; n++)
                    acc[m][n] = __builtin_amdgcn_mfma_f32_16x16x32_bf16(af, bfr[n], acc[m][n], 0, 0, 0);
            }
        }
        __syncthreads();   // all MFMA done: LDS reusable (next stage / epilogue scratch)

        if (ki == KI - 1) {
            // ---- epilogue for tile mt: acc row = (lane>>4)*4 + i, col = lane&15 ----
            const int row0 = (bx0 + mt) * GBM;
            if constexpr (BF16OUT) {
                unsigned short* Cb = (unsigned short*)Cout;
#pragma unroll
                for (int n = 0; n < 4; n++) {
                    int cl = wn * 64 + n * 16 + (l & 15);
                    float bv = bias ? bias[col0 + cl] : 0.0f;
#pragma unroll
                    for (int m = 0; m < 4; m++) {
                        int rbase = wm * 64 + m * 16 + (l >> 4) * 4;
#pragma unroll
                        for (int i = 0; i < 4; i++) {
                            int rl = rbase + i;
                            float o = acc[m][n][i] + bv;
                            if (EPI == 1) o = silu_f(o);
                            int chunk = cl >> 3;
                            int phys = chunk ^ (rl & 15);
                            smem[rl * 128 + phys * 8 + (cl & 7)] = f2bf(o);
                        }
                    }
                }
                __syncthreads();
                int orow = tid >> 1, hf = tid & 1;
                int rr = row0 + orow;
                if (rr < M) {
                    unsigned short* crow = Cb + (size_t)rr * Nc + col0;
#pragma unroll
                    for (int c8 = 0; c8 < 8; c8++) {
                        int chunk = hf * 8 + c8;
                        int phys = chunk ^ (orow & 15);
                        uint4 v = *(uint4*)&smem[orow * 128 + phys * 8];
                        *(uint4*)(crow + chunk * 8) = v;
                    }
                }
                __syncthreads();  // epilogue LDS reads done before next stage overwrites
            } else {
                float* Cf = (float*)Cout;
                const int cbase = col0 + wn * 64 + (l & 15);
#pragma unroll
                for (int n = 0; n < 4; n++) {
                    int c = cbase + n * 16;
                    float bv = bias ? bias[c] : 0.0f;
#pragma unroll
                    for (int m = 0; m < 4; m++) {
                        int rbase = row0 + wm * 64 + m * 16 + (l >> 4) * 4;
#pragma unroll
                        for (int i = 0; i < 4; i++) {
                            int rr = rbase + i;
                            if (rr >= M) continue;
                            float o = acc[m][n][i];
                            if (EPI == 2) {
                                float cf = (float)cnt[rr];
                                o = (o + cf * bv) / fmaxf(cf, 1.0f);
                            } else {
                                o += bv;
                                if (EPI == 1) o = silu_f(o);
                            }
                            size_t off = (size_t)rr * Nc + c;
                            if (EPI == 3) Cf[off] += o;
                            else          Cf[off] = o;
                        }
                    }
                }
            }
            if (it + 1 < NIT) {
#pragma unroll
                for (int m = 0; m < 4; m++)
#pragma unroll
                    for (int n = 0; n < 4; n++) acc[m][n] = f32x4{0.f, 0.f, 0.f, 0.f};
            }
        }
        // advance & swap prefetch regs
        if (++ki == KI) { ki = 0; ++mt; }
#pragma unroll
        for (int ci = 0; ci < 4; ci++) { cA[ci] = nA[ci]; cB[ci] = nB[ci]; }
    }
}

// ---------------- fused msg + CSR aggregation (bf16 in, fp32 accum, bf16 u, NO atomics) ----------------
// Pab[node][512]: cols 0-255 = Pa (src term), cols 256-511 = Pb (dst term)
// FIRST chunk: every node WRITES u (zeros if no edges -> u fully initialized, no memset).
// Later chunks: RMW, early-exit when no edges in range. Chunks stream-serialized -> race-free.
template <bool FIRST>
__global__ void agg_kernel(const unsigned short* __restrict__ Pab,
                           const unsigned short* __restrict__ Pe, const int* __restrict__ esrc,
                           const int* __restrict__ rowptr,
                           unsigned short* __restrict__ u, int e0, int e1)
{
    int node = blockIdx.x * 4 + (threadIdx.x >> 6);
    if (node >= NN) return;
    int beg = rowptr[node], end = rowptr[node + 1];
    int lo = beg > e0 ? beg : e0;
    int hi = end < e1 ? end : e1;
    if (!FIRST && lo >= hi) return;
    int lane = threadIdx.x & 63;
    int j = lane * 4;
    float a0 = 0.f, a1 = 0.f, a2 = 0.f, a3 = 0.f;
    if (lo < hi) {
        ushort4 pb4 = *(const ushort4*)(Pab + (size_t)node * 512 + 256 + j);
        float b0 = bf2f(pb4.x), b1 = bf2f(pb4.y), b2 = bf2f(pb4.z), b3 = bf2f(pb4.w);
        int p = lo;
        int src = esrc[p];
        ushort4 pa = *(const ushort4*)(Pab + (size_t)src * 512 + j);
        ushort4 pe = *(const ushort4*)(Pe + (size_t)(p - e0) * HH + j);
        for (;;) {
            ushort4 cpa = pa, cpe = pe;
            int np = p + 1;
            if (np < hi) {
                int s2 = esrc[np];
                pa = *(const ushort4*)(Pab + (size_t)s2 * 512 + j);
                pe = *(const ushort4*)(Pe + (size_t)(np - e0) * HH + j);
            }
            a0 += silu_f(bf2f(cpa.x) + b0 + bf2f(cpe.x));
            a1 += silu_f(bf2f(cpa.y) + b1 + bf2f(cpe.y));
            a2 += silu_f(bf2f(cpa.z) + b2 + bf2f(cpe.z));
            a3 += silu_f(bf2f(cpa.w) + b3 + bf2f(cpe.w));
            if (np >= hi) break;
            p = np;
        }
    }
    unsigned short* up = u + (size_t)node * HH + j;
    if (!FIRST) {
        ushort4 uo = *(const ushort4*)up;
        a0 += bf2f(uo.x); a1 += bf2f(uo.y); a2 += bf2f(uo.z); a3 += bf2f(uo.w);
    }
    ushort4 o;
    o.x = f2bf(a0); o.y = f2bf(a1); o.z = f2bf(a2); o.w = f2bf(a3);
    *(ushort4*)up = o;
}

// ---------------- edge_index normalization (int64-vs-int32 autodetect) ----------------
// Benign-race plain store (all writers store 0) -- NOT atomic: same-address atomics
// serialized ~5000 waves and cost 59 us/launch.
__global__ void detect_kernel(const uint32_t* __restrict__ w, int* flag)
{
    int i = blockIdx.x * 256 + threadIdx.x;
    bool bad = false;
    if (i < NE) {  // only scan first half -> reads stay in-bounds for either layout
        uint32_t lo = w[2 * i], hi = w[2 * i + 1];
        bad = (hi != 0u) || (lo >= (uint32_t)NN);
    }
    if (__any(bad)) {
        if ((threadIdx.x & 63) == 0) *flag = 0;
    }
}
__global__ void convert_kernel(const uint32_t* __restrict__ w, const int* __restrict__ flag,
                               int* __restrict__ out)
{
    int i = blockIdx.x * 256 + threadIdx.x;
    if (i >= 2 * NE) return;
    out[i] = (*flag) ? (int)w[2 * i] : (int)w[i];
}
__global__ void deg_kernel(const int* __restrict__ idx, int* __restrict__ cnt)
{
    int e = blockIdx.x * 256 + threadIdx.x;
    if (e < NE) atomicAdd(cnt + idx[NE + e], 1);
}

// ---------------- exclusive prefix scan of cnt[NN] -> rowptr[NN+1], single block ----------------
__global__ void scan_kernel(const int* __restrict__ cnt, int* __restrict__ rowptr)
{
    __shared__ int part[1024];
    const int T = 1024, PER = (NN + T - 1) / T;
    int t = threadIdx.x;
    int base = t * PER;
    int s = 0;
    for (int i = 0; i < PER; i++) {
        int idx = base + i;
        if (idx < NN) s += cnt[idx];
    }
    part[t] = s;
    __syncthreads();
    for (int off = 1; off < T; off <<= 1) {
        int v = (t >= off) ? part[t - off] : 0;
        __syncthreads();
        part[t] += v;
        __syncthreads();
    }
    int run = (t == 0) ? 0 : part[t - 1];
    for (int i = 0; i < PER; i++) {
        int idx = base + i;
        if (idx < NN) { rowptr[idx] = run; run += cnt[idx]; }
    }
    if (t == T - 1) rowptr[NN] = part[T - 1];
}

// ---------------- scatter edges into dst-sorted order ----------------
__global__ void fill_kernel(const int* __restrict__ idx, const int* __restrict__ rowptr,
                            int* __restrict__ fillc, int* __restrict__ esrc,
                            int* __restrict__ eorig)
{
    int e = blockIdx.x * 256 + threadIdx.x;
    if (e >= NE) return;
    int dst = idx[NE + e];
    int pos = rowptr[dst] + atomicAdd(fillc + dst, 1);
    esrc[pos]  = idx[e];
    eorig[pos] = e;
}

// ---------------- launcher ----------------
extern "C" void kernel_launch(void* const* d_in, const int* in_sizes, int n_in,
                              void* d_out, int out_size, void* d_ws, size_t ws_size,
                              hipStream_t stream)
{
    const float* node_state = (const float*)d_in[0];
    const float* edge_attr  = (const float*)d_in[1];
    const float* nn_g = (const float*)d_in[2];
    const float* nn_b = (const float*)d_in[3];
    const float* mn_g = (const float*)d_in[4];
    const float* mn_b = (const float*)d_in[5];
    const float* eW1  = (const float*)d_in[6];
    const float* eb1  = (const float*)d_in[7];
    const float* eW2  = (const float*)d_in[8];
    const float* eb2  = (const float*)d_in[9];
    const float* nW1  = (const float*)d_in[10];
    const float* nb1  = (const float*)d_in[11];
    const float* nW2  = (const float*)d_in[12];
    const float* nb2  = (const float*)d_in[13];
    const uint32_t* eidx_raw = (const uint32_t*)d_in[14];

    const size_t SZ = (size_t)NN * HH;                  // 5,120,000
    unsigned short* hn  = (unsigned short*)d_ws;        // NN*HH bf16 (10.24 MB)
    unsigned short* u   = hn + SZ;                      // NN*HH bf16 (10.24 MB)
    unsigned short* Pab = u + SZ;                       // NN*512 bf16 (20.48 MB)
    unsigned short* eas = Pab + (size_t)NN * 512;       // NE*EDK bf16 (40.96 MB)
    unsigned short* Pe  = eas + (size_t)NE * EDK;       // ECH*HH bf16 (81.92 MB)
    //   aliases inside the Pe region (all used only after chunks complete):
    float* aggp = (float*)Pe;                                                   // NN*HH fp32 (20.48 MB)
    unsigned short* aggb = (unsigned short*)((char*)Pe + 22000000);             // NN*HH bf16 (10.24 MB)
    unsigned short* zb   = (unsigned short*)((char*)Pe + 34000000);             // NN*512 bf16 (20.48 MB)
    unsigned short* wbuf = Pe + (size_t)ECH * HH;       // 4*WSTEP bf16 (4.85 MB)
    int* idx32  = (int*)(wbuf + 4 * WSTEP);
    int* esrc   = idx32 + 2 * NE;
    int* eorig  = esrc + NE;
    int* rowptr = eorig + NE;      // NN+1
    int* cnt    = rowptr + NN + 1;
    int* fillc  = cnt + NN;
    int* flag   = fillc + NN;
    size_t needed = ((size_t)(flag + 1) - (size_t)d_ws);
    if (ws_size < needed) return;  // insufficient scratch: fail verification, don't crash

    float* h = (float*)d_out;

    hipMemcpyAsync(h, node_state, SZ * sizeof(float), hipMemcpyDeviceToDevice, stream);

    // ---- preprocessing ----
    wtr_kernel<<<4 * 592, 256, 0, stream>>>(eW1, eW2, nW1, nW2, wbuf);
    hipMemsetAsync(flag, 0xFF, sizeof(int), stream);
    detect_kernel<<<(NE + 255) / 256, 256, 0, stream>>>(eidx_raw, flag);
    convert_kernel<<<(2 * NE + 255) / 256, 256, 0, stream>>>(eidx_raw, flag, idx32);
    hipMemsetAsync(cnt, 0, NN * sizeof(int), stream);
    deg_kernel<<<(NE + 255) / 256, 256, 0, stream>>>(idx32, cnt);
    scan_kernel<<<1, 1024, 0, stream>>>(cnt, rowptr);
    hipMemsetAsync(fillc, 0, NN * sizeof(int), stream);
    fill_kernel<<<(NE + 255) / 256, 256, 0, stream>>>(idx32, rowptr, fillc, esrc, eorig);
    easort_kernel<<<(NE * 16) / 256, 256, 0, stream>>>(edge_attr, eorig, eas);

    const dim3 gN2((NN + GBM - 1) / GBM, 2);   // Nc=256, TM=1
    const dim3 gN4((NN + GBM - 1) / GBM, 4);   // Nc=512, TM=1
    const dim3 gPe(ECH / (GBM * 2), 2);        // Nc=256, TM=2 (625x2 blocks)

    for (int s = 0; s < NSTEPS; s++) {
        const unsigned short* wb = wbuf + (size_t)s * WSTEP;
        const unsigned short* WabT = wb;            // [512][256]: Wa^T rows 0-255, Wb^T rows 256-511
        const unsigned short* WcT  = wb + 131072;   // [256][64]
        const unsigned short* eW2T = wb + 147456;   // [256][256]
        const unsigned short* nW1T = wb + 212992;   // [512][512]
        const unsigned short* nW2T = wb + 475136;   // [256][512]
        const float* eb1s = eb1 + (size_t)s * HH;
        const float* eb2s = eb2 + (size_t)s * HH;
        const float* nb1s = nb1 + (size_t)s * 512;
        const float* nb2s = nb2 + (size_t)s * HH;

        // hn = bf16(LN(h))
        ln_kernel<<<NN / 4, 256, 0, stream>>>(h, nn_g + s * HH, nn_b + s * HH, hn, NN);
        // Pab = bf16(hn @ [Wa|Wb])  (one GEMM, Nc=512, bf16 A)
        mgemm<0, 3, true, 1><<<gN4, 256, 0, stream>>>(hn, nullptr, HH, WabT, nullptr, nullptr, Pab, NN, 512, HH);
        // u = segment_sum over sorted edges of silu(Pa[src]+Pb[dst]+ea_sorted@Wc+eb1)
        {
            // chunk 0 (writes u, including zero rows)
            mgemm<0, 3, true, 2><<<gPe, 256, 0, stream>>>(eas, nullptr, EDK, WcT, eb1s, nullptr, Pe, ECH, HH, EDK);
            agg_kernel<true><<<(NN + 3) / 4, 256, 0, stream>>>(Pab, Pe, esrc, rowptr, u, 0, ECH);
            // chunk 1 (RMW)
            mgemm<0, 3, true, 2><<<gPe, 256, 0, stream>>>(eas + (size_t)ECH * EDK, nullptr, EDK, WcT, eb1s, nullptr, Pe, ECH, HH, EDK);
            agg_kernel<false><<<(NN + 3) / 4, 256, 0, stream>>>(Pab, Pe, esrc, rowptr, u, ECH, NE);
        }
        // aggp = (u @ eW2 + cnt*eb2)/max(cnt,1)  [fp32] ; aggb = bf16(LN(aggp))
        mgemm<2, 3, false, 1><<<gN2, 256, 0, stream>>>(u, nullptr, HH, eW2T, eb2s, cnt, aggp, NN, HH, HH);
        ln_kernel<<<NN / 4, 256, 0, stream>>>(aggp, mn_g + s * HH, mn_b + s * HH, aggb, NN);
        // zb = bf16(silu([hn, aggb] @ nW1 + nb1))
        mgemm<1, 4, true, 1><<<gN4, 256, 0, stream>>>(hn, aggb, HH, nW1T, nb1s, nullptr, zb, NN, 512, 512);
        // h += zb @ nW2 + nb2
        mgemm<3, 3, false, 1><<<gN2, 256, 0, stream>>>(zb, nullptr, 512, nW2T, nb2s, nullptr, h, NN, HH, 512);
    }
}

// Round 7
// 1721.211 us; speedup vs baseline: 1.1866x; 1.1866x over previous
//
#include <hip/hip_runtime.h>
#include <hip/hip_bf16.h>
#include <stdint.h>

// Problem constants (from reference)
#define NN 20000     // nodes
#define NE 320000    // edges
#define HH 256       // hidden
#define EDK 64       // edge_dim
#define NSTEPS 4
#define ECH 160000   // edges per chunk (Pe buffer covers one chunk)
#define WSTEP 606208 // bf16 elems of transposed weights per step
#define MT1 157      // ceil(NN/128)

typedef __attribute__((ext_vector_type(8))) short bf16x8;
typedef __attribute__((ext_vector_type(4))) float f32x4;

__device__ __forceinline__ float silu_f(float x) { return x / (1.0f + __expf(-x)); }

__device__ __forceinline__ unsigned short f2bf(float f) {
    __hip_bfloat16 h = __float2bfloat16(f);
    return __builtin_bit_cast(unsigned short, h);
}
__device__ __forceinline__ float bf2f(unsigned short u) {
    unsigned int x = ((unsigned int)u) << 16;
    return __builtin_bit_cast(float, x);
}

// ---------------- LayerNorm: fp32 in, bf16 out; one wave per row of 256 ----------------
__global__ void ln_kernel(const float* __restrict__ x, const float* __restrict__ g,
                          const float* __restrict__ b, unsigned short* __restrict__ y, int M)
{
    int row  = blockIdx.x * 4 + (threadIdx.x >> 6);
    int lane = threadIdx.x & 63;
    if (row >= M) return;
    float4 v = *(const float4*)(x + (size_t)row * HH + lane * 4);
    float s  = v.x + v.y + v.z + v.w;
    float ss = v.x*v.x + v.y*v.y + v.z*v.z + v.w*v.w;
#pragma unroll
    for (int off = 32; off > 0; off >>= 1) {
        s  += __shfl_down(s, off);
        ss += __shfl_down(ss, off);
    }
    float mean = __shfl(s, 0) * (1.0f / HH);
    float ms   = __shfl(ss, 0) * (1.0f / HH);
    float rstd = rsqrtf(ms - mean * mean + 1e-5f);
    float4 gg = *(const float4*)(g + lane * 4);
    float4 bb = *(const float4*)(b + lane * 4);
    ushort4 o;
    o.x = f2bf((v.x - mean) * rstd * gg.x + bb.x);
    o.y = f2bf((v.y - mean) * rstd * gg.y + bb.y);
    o.z = f2bf((v.z - mean) * rstd * gg.z + bb.z);
    o.w = f2bf((v.w - mean) * rstd * gg.w + bb.w);
    *(ushort4*)(y + (size_t)row * HH + lane * 4) = o;
}

// ---------------- weight transpose + bf16 convert: all 24 matrices, one launch ----------------
__global__ void wtr_kernel(const float* __restrict__ eW1, const float* __restrict__ eW2,
                           const float* __restrict__ nW1, const float* __restrict__ nW2,
                           unsigned short* __restrict__ wbuf)
{
    int bx = blockIdx.x;
    int s  = bx / 592, t = bx % 592;
    const float* e1 = eW1 + (size_t)s * 576 * 256;
    unsigned short* wb = wbuf + (size_t)s * WSTEP;
    const float* src; unsigned short* dst; int K, N;
    if      (t < 64)  { src = e1;                          K = 256; N = 256; dst = wb; }
    else if (t < 128) { src = e1 + 65536;                  K = 256; N = 256; dst = wb + 65536;  t -= 64; }
    else if (t < 144) { src = e1 + 131072;                 K = 64;  N = 256; dst = wb + 131072; t -= 128; }
    else if (t < 208) { src = eW2 + (size_t)s * 65536;     K = 256; N = 256; dst = wb + 147456; t -= 144; }
    else if (t < 464) { src = nW1 + (size_t)s * 262144;    K = 512; N = 512; dst = wb + 212992; t -= 208; }
    else              { src = nW2 + (size_t)s * 131072;    K = 512; N = 256; dst = wb + 475136; t -= 464; }
    int ntn = N >> 5;
    int tk = t / ntn, tn = t % ntn;
    int k0 = tk * 32, n0 = tn * 32;
    __shared__ float ts[32][33];
    int tx = threadIdx.x & 31, ty = threadIdx.x >> 5;
#pragma unroll
    for (int i = 0; i < 4; i++)
        ts[ty + i * 8][tx] = src[(size_t)(k0 + ty + i * 8) * N + n0 + tx];
    __syncthreads();
#pragma unroll
    for (int i = 0; i < 4; i++)
        dst[(size_t)(n0 + ty + i * 8) * K + k0 + tx] = f2bf(ts[tx][ty + i * 8]);
}

// ---------------- edge_attr gather-to-sorted-order + bf16 convert (once per launch) ----------------
__global__ void easort_kernel(const float* __restrict__ ea, const int* __restrict__ eorig,
                              unsigned short* __restrict__ out)
{
    int gid = blockIdx.x * 256 + threadIdx.x;
    int p = gid >> 4, q = gid & 15;
    if (p >= NE) return;
    float4 v = *(const float4*)(ea + (size_t)eorig[p] * EDK + q * 4);
    ushort4 o;
    o.x = f2bf(v.x); o.y = f2bf(v.y); o.z = f2bf(v.z); o.w = f2bf(v.w);
    *(ushort4*)(out + (size_t)p * EDK + q * 4) = o;
}

// ---------------- MFMA bf16 GEMM body (round-5 structure, GBN templated) ----------------
// C[M,Nc] = A[M,K] @ BT[Nc,K]^T (+epilogue)
// EPI: 0 = acc+bias   1 = silu(acc+bias)   2 = (acc + cnt*bias)/max(cnt,1)   3 = C += acc+bias
// ASRC: 3 = bf16 rows (lda)   4 = concat bf16 A|A2 (ld 256 each)
#define GBM 128
#define GBK 64
template <int EPI, int ASRC, bool BF16OUT, int GBNT>
__device__ __forceinline__ void mgemm_body(
    int bxv, int byv,
    const void* __restrict__ A, const void* __restrict__ A2, int lda,
    const unsigned short* __restrict__ BT,
    const float* __restrict__ bias, const int* __restrict__ cnt,
    void* __restrict__ Cout, int M, int Nc, int K)
{
    constexpr int NF   = GBNT / 32;   // B n-frags per wave (4 or 2), also B chunks/thread
    constexpr int TPRB = 8 / NF;      // staging threads per B row (2 or 4)
    constexpr int CPR  = GBNT / 8;    // 16B chunks per C row in epilogue repack
    __shared__ unsigned short smem[(GBM + GBNT) * GBK];
    unsigned short* lsA = smem;
    unsigned short* lsB = smem + GBM * GBK;
    const int tid = threadIdx.x;
    const int col0 = byv * GBNT;
    const int rA = tid >> 1, half = tid & 1;      // A staging row / half-row
    const int rB = tid / TPRB, subB = tid % TPRB; // B staging row / sub
    const int w = tid >> 6, l = tid & 63;         // wave id / lane
    const int wm = w >> 1, wn = w & 1;            // 2x2 wave grid

    const unsigned short* Ab  = (const unsigned short*)A;
    const unsigned short* A2b = (const unsigned short*)A2;
    const int growA = bxv * GBM + rA;
    const bool aval = (growA < M);
    const unsigned short* brow = BT + (size_t)(col0 + rB) * K;

    f32x4 acc[4][NF] = {};

    for (int k0 = 0; k0 < K; k0 += GBK) {
        // ---- stage A (16B-chunk XOR swizzle) ----
        {
            uint4 q[4] = {};
            if (aval) {
                const unsigned short* ap;
                if constexpr (ASRC == 4)
                    ap = ((k0 < 256) ? Ab : A2b) + (size_t)growA * 256 + (k0 & 255) + half * 32;
                else
                    ap = Ab + (size_t)growA * lda + k0 + half * 32;
#pragma unroll
                for (int ci = 0; ci < 4; ci++) q[ci] = ((const uint4*)ap)[ci];
            }
#pragma unroll
            for (int ci = 0; ci < 4; ci++) {
                int slot = half * 4 + ci;
                int phys = slot ^ (rA & 7);
                *(uint4*)&lsA[rA * GBK + phys * 8] = q[ci];
            }
        }
        // ---- stage B: straight bf16 copy, same swizzle ----
        {
            const unsigned short* bp = brow + k0 + subB * (NF * 8);
#pragma unroll
            for (int ci = 0; ci < NF; ci++) {
                uint4 q = ((const uint4*)bp)[ci];
                int slot = subB * NF + ci;
                int phys = slot ^ (rB & 7);
                *(uint4*)&lsB[rB * GBK + phys * 8] = q;
            }
        }
        __syncthreads();
        // ---- 2 k-steps of 16x16x32 MFMAs ----
#pragma unroll
        for (int ks = 0; ks < 2; ks++) {
            bf16x8 bfr[NF];
#pragma unroll
            for (int n = 0; n < NF; n++) {
                int rn = wn * (GBNT / 2) + n * 16 + (l & 15);
                int phys = (ks * 4 + (l >> 4)) ^ (rn & 7);
                bfr[n] = *(bf16x8*)&lsB[rn * GBK + phys * 8];
            }
#pragma unroll
            for (int m = 0; m < 4; m++) {
                int rm = wm * 64 + m * 16 + (l & 15);
                int phys = (ks * 4 + (l >> 4)) ^ (rm & 7);
                bf16x8 af = *(bf16x8*)&lsA[rm * GBK + phys * 8];
#pragma unroll
                for (int n = 0; n < NF; n++)
                    acc[m][n] = __builtin_amdgcn_mfma_f32_16x16x32_bf16(af, bfr[n], acc[m][n], 0, 0, 0);
            }
        }
        __syncthreads();
    }

    // ---- epilogue: acc row = (lane>>4)*4 + i, col = lane&15 ----
    const int row0 = bxv * GBM;
    if constexpr (BF16OUT) {
        // stage to LDS ([128][GBNT] bf16, 16B-chunk XOR swizzle), then stream 16B stores
        unsigned short* Cb = (unsigned short*)Cout;
#pragma unroll
        for (int n = 0; n < NF; n++) {
            int cl = wn * (GBNT / 2) + n * 16 + (l & 15);
            float bv = bias ? bias[col0 + cl] : 0.0f;
#pragma unroll
            for (int m = 0; m < 4; m++) {
                int rbase = wm * 64 + m * 16 + (l >> 4) * 4;
#pragma unroll
                for (int i = 0; i < 4; i++) {
                    int rl = rbase + i;
                    float o = acc[m][n][i] + bv;
                    if (EPI == 1) o = silu_f(o);
                    int chunk = cl >> 3;
                    int phys = chunk ^ (rl & (CPR - 1));
                    smem[rl * GBNT + phys * 8 + (cl & 7)] = f2bf(o);
                }
            }
        }
        __syncthreads();
        int orow = tid >> 1, hf = tid & 1;
        int rr = row0 + orow;
        if (rr < M) {
            unsigned short* crow = Cb + (size_t)rr * Nc + col0;
#pragma unroll
            for (int c8 = 0; c8 < CPR / 2; c8++) {
                int chunk = hf * (CPR / 2) + c8;
                int phys = chunk ^ (orow & (CPR - 1));
                uint4 v = *(uint4*)&smem[orow * GBNT + phys * 8];
                *(uint4*)(crow + chunk * 8) = v;
            }
        }
    } else {
        float* Cf = (float*)Cout;
        const int cbase = col0 + wn * (GBNT / 2) + (l & 15);
#pragma unroll
        for (int n = 0; n < NF; n++) {
            int c = cbase + n * 16;
            float bv = bias ? bias[c] : 0.0f;
#pragma unroll
            for (int m = 0; m < 4; m++) {
                int rbase = row0 + wm * 64 + m * 16 + (l >> 4) * 4;
#pragma unroll
                for (int i = 0; i < 4; i++) {
                    int rr = rbase + i;
                    if (rr >= M) continue;
                    float o = acc[m][n][i];
                    if (EPI == 2) {
                        float cf = (float)cnt[rr];
                        o = (o + cf * bv) / fmaxf(cf, 1.0f);
                    } else {
                        o += bv;
                        if (EPI == 1) o = silu_f(o);
                    }
                    size_t off = (size_t)rr * Nc + c;
                    if (EPI == 3) Cf[off] += o;
                    else          Cf[off] = o;
                }
            }
        }
    }
}

template <int EPI, int ASRC, bool BF16OUT, int GBNT>
__global__ __launch_bounds__(256) void mgemm(
    const void* __restrict__ A, const void* __restrict__ A2, int lda,
    const unsigned short* __restrict__ BT,
    const float* __restrict__ bias, const int* __restrict__ cnt,
    void* __restrict__ Cout, int M, int Nc, int K)
{
    mgemm_body<EPI, ASRC, BF16OUT, GBNT>(blockIdx.x, blockIdx.y, A, A2, lda, BT, bias, cnt,
                                         Cout, M, Nc, K);
}

// ---------------- dual dispatch: Pab GEMM + Pe chunk-0 GEMM in ONE launch ----------------
// blocks [0,628): Pab = hn @ WabT  (157 x 4 col-tiles)
// blocks [628, 628+2500): Pe = eas_c0 @ WcT + eb1  (1250 x 2 col-tiles)
__global__ __launch_bounds__(256) void dual_kernel(
    const unsigned short* __restrict__ hn, const unsigned short* __restrict__ WabT,
    unsigned short* __restrict__ Pab,
    const unsigned short* __restrict__ eas, const unsigned short* __restrict__ WcT,
    const float* __restrict__ eb1s, unsigned short* __restrict__ Pe)
{
    const int split = MT1 * 4;  // 628
    int bid = blockIdx.x;
    int bx, by, lda, M, Nc, K;
    const void* A; const unsigned short* BT; const float* bias; void* C;
    if (bid < split) {
        bx = bid % MT1; by = bid / MT1;
        A = hn; lda = HH; BT = WabT; bias = nullptr; C = Pab; M = NN; Nc = 512; K = HH;
    } else {
        int id2 = bid - split;
        bx = id2 % (ECH / GBM); by = id2 / (ECH / GBM);
        A = eas; lda = EDK; BT = WcT; bias = eb1s; C = Pe; M = ECH; Nc = HH; K = EDK;
    }
    mgemm_body<0, 3, true, 128>(bx, by, A, nullptr, lda, BT, bias, nullptr, C, M, Nc, K);
}

// ---------------- fused msg + CSR aggregation (bf16 in, fp32 accum, bf16 u, NO atomics) ----------------
template <bool FIRST>
__global__ void agg_kernel(const unsigned short* __restrict__ Pab,
                           const unsigned short* __restrict__ Pe, const int* __restrict__ esrc,
                           const int* __restrict__ rowptr,
                           unsigned short* __restrict__ u, int e0, int e1)
{
    int node = blockIdx.x * 4 + (threadIdx.x >> 6);
    if (node >= NN) return;
    int beg = rowptr[node], end = rowptr[node + 1];
    int lo = beg > e0 ? beg : e0;
    int hi = end < e1 ? end : e1;
    if (!FIRST && lo >= hi) return;
    int lane = threadIdx.x & 63;
    int j = lane * 4;
    float a0 = 0.f, a1 = 0.f, a2 = 0.f, a3 = 0.f;
    if (lo < hi) {
        ushort4 pb4 = *(const ushort4*)(Pab + (size_t)node * 512 + 256 + j);
        float b0 = bf2f(pb4.x), b1 = bf2f(pb4.y), b2 = bf2f(pb4.z), b3 = bf2f(pb4.w);
        int p = lo;
        int src = esrc[p];
        ushort4 pa = *(const ushort4*)(Pab + (size_t)src * 512 + j);
        ushort4 pe = *(const ushort4*)(Pe + (size_t)(p - e0) * HH + j);
        for (;;) {
            ushort4 cpa = pa, cpe = pe;
            int np = p + 1;
            if (np < hi) {
                int s2 = esrc[np];
                pa = *(const ushort4*)(Pab + (size_t)s2 * 512 + j);
                pe = *(const ushort4*)(Pe + (size_t)(np - e0) * HH + j);
            }
            a0 += silu_f(bf2f(cpa.x) + b0 + bf2f(cpe.x));
            a1 += silu_f(bf2f(cpa.y) + b1 + bf2f(cpe.y));
            a2 += silu_f(bf2f(cpa.z) + b2 + bf2f(cpe.z));
            a3 += silu_f(bf2f(cpa.w) + b3 + bf2f(cpe.w));
            if (np >= hi) break;
            p = np;
        }
    }
    unsigned short* up = u + (size_t)node * HH + j;
    if (!FIRST) {
        ushort4 uo = *(const ushort4*)up;
        a0 += bf2f(uo.x); a1 += bf2f(uo.y); a2 += bf2f(uo.z); a3 += bf2f(uo.w);
    }
    ushort4 o;
    o.x = f2bf(a0); o.y = f2bf(a1); o.z = f2bf(a2); o.w = f2bf(a3);
    *(ushort4*)up = o;
}

// ---------------- edge_index normalization (int64-vs-int32 autodetect) ----------------
// Benign-race plain store (all writers store 0) -- NOT atomic (same-address atomics = 59 us).
__global__ void detect_kernel(const uint32_t* __restrict__ w, int* flag)
{
    int i = blockIdx.x * 256 + threadIdx.x;
    bool bad = false;
    if (i < NE) {
        uint32_t lo = w[2 * i], hi = w[2 * i + 1];
        bad = (hi != 0u) || (lo >= (uint32_t)NN);
    }
    if (__any(bad)) {
        if ((threadIdx.x & 63) == 0) *flag = 0;
    }
}
__global__ void convert_kernel(const uint32_t* __restrict__ w, const int* __restrict__ flag,
                               int* __restrict__ out)
{
    int i = blockIdx.x * 256 + threadIdx.x;
    if (i >= 2 * NE) return;
    out[i] = (*flag) ? (int)w[2 * i] : (int)w[i];
}
__global__ void deg_kernel(const int* __restrict__ idx, int* __restrict__ cnt)
{
    int e = blockIdx.x * 256 + threadIdx.x;
    if (e < NE) atomicAdd(cnt + idx[NE + e], 1);
}

// ---------------- exclusive prefix scan of cnt[NN] -> rowptr[NN+1], single block ----------------
__global__ void scan_kernel(const int* __restrict__ cnt, int* __restrict__ rowptr)
{
    __shared__ int part[1024];
    const int T = 1024, PER = (NN + T - 1) / T;
    int t = threadIdx.x;
    int base = t * PER;
    int s = 0;
    for (int i = 0; i < PER; i++) {
        int idx = base + i;
        if (idx < NN) s += cnt[idx];
    }
    part[t] = s;
    __syncthreads();
    for (int off = 1; off < T; off <<= 1) {
        int v = (t >= off) ? part[t - off] : 0;
        __syncthreads();
        part[t] += v;
        __syncthreads();
    }
    int run = (t == 0) ? 0 : part[t - 1];
    for (int i = 0; i < PER; i++) {
        int idx = base + i;
        if (idx < NN) { rowptr[idx] = run; run += cnt[idx]; }
    }
    if (t == T - 1) rowptr[NN] = part[T - 1];
}

// ---------------- scatter edges into dst-sorted order ----------------
__global__ void fill_kernel(const int* __restrict__ idx, const int* __restrict__ rowptr,
                            int* __restrict__ fillc, int* __restrict__ esrc,
                            int* __restrict__ eorig)
{
    int e = blockIdx.x * 256 + threadIdx.x;
    if (e >= NE) return;
    int dst = idx[NE + e];
    int pos = rowptr[dst] + atomicAdd(fillc + dst, 1);
    esrc[pos]  = idx[e];
    eorig[pos] = e;
}

// ---------------- launcher ----------------
extern "C" void kernel_launch(void* const* d_in, const int* in_sizes, int n_in,
                              void* d_out, int out_size, void* d_ws, size_t ws_size,
                              hipStream_t stream)
{
    const float* node_state = (const float*)d_in[0];
    const float* edge_attr  = (const float*)d_in[1];
    const float* nn_g = (const float*)d_in[2];
    const float* nn_b = (const float*)d_in[3];
    const float* mn_g = (const float*)d_in[4];
    const float* mn_b = (const float*)d_in[5];
    const float* eW1  = (const float*)d_in[6];
    const float* eb1  = (const float*)d_in[7];
    const float* eW2  = (const float*)d_in[8];
    const float* eb2  = (const float*)d_in[9];
    const float* nW1  = (const float*)d_in[10];
    const float* nb1  = (const float*)d_in[11];
    const float* nW2  = (const float*)d_in[12];
    const float* nb2  = (const float*)d_in[13];
    const uint32_t* eidx_raw = (const uint32_t*)d_in[14];

    const size_t SZ = (size_t)NN * HH;                  // 5,120,000
    unsigned short* hn  = (unsigned short*)d_ws;        // NN*HH bf16 (10.24 MB)
    unsigned short* u   = hn + SZ;                      // NN*HH bf16 (10.24 MB)
    unsigned short* Pab = u + SZ;                       // NN*512 bf16 (20.48 MB)
    unsigned short* eas = Pab + (size_t)NN * 512;       // NE*EDK bf16 (40.96 MB)
    unsigned short* Pe  = eas + (size_t)NE * EDK;       // ECH*HH bf16 (81.92 MB)
    //   aliases inside the Pe region (all used only after chunks complete):
    float* aggp = (float*)Pe;                                                   // NN*HH fp32 (20.48 MB)
    unsigned short* aggb = (unsigned short*)((char*)Pe + 22000000);             // NN*HH bf16 (10.24 MB)
    unsigned short* zb   = (unsigned short*)((char*)Pe + 34000000);             // NN*512 bf16 (20.48 MB)
    unsigned short* wbuf = Pe + (size_t)ECH * HH;       // 4*WSTEP bf16 (4.85 MB)
    int* idx32  = (int*)(wbuf + 4 * WSTEP);
    int* esrc   = idx32 + 2 * NE;
    int* eorig  = esrc + NE;
    int* rowptr = eorig + NE;      // NN+1
    int* cnt    = rowptr + NN + 1;
    int* fillc  = cnt + NN;
    int* flag   = fillc + NN;
    size_t needed = ((size_t)(flag + 1) - (size_t)d_ws);
    if (ws_size < needed) return;  // insufficient scratch: fail verification, don't crash

    float* h = (float*)d_out;

    hipMemcpyAsync(h, node_state, SZ * sizeof(float), hipMemcpyDeviceToDevice, stream);

    // ---- preprocessing ----
    wtr_kernel<<<4 * 592, 256, 0, stream>>>(eW1, eW2, nW1, nW2, wbuf);
    hipMemsetAsync(flag, 0xFF, sizeof(int), stream);
    detect_kernel<<<(NE + 255) / 256, 256, 0, stream>>>(eidx_raw, flag);
    convert_kernel<<<(2 * NE + 255) / 256, 256, 0, stream>>>(eidx_raw, flag, idx32);
    hipMemsetAsync(cnt, 0, NN * sizeof(int), stream);
    deg_kernel<<<(NE + 255) / 256, 256, 0, stream>>>(idx32, cnt);
    scan_kernel<<<1, 1024, 0, stream>>>(cnt, rowptr);
    hipMemsetAsync(fillc, 0, NN * sizeof(int), stream);
    fill_kernel<<<(NE + 255) / 256, 256, 0, stream>>>(idx32, rowptr, fillc, esrc, eorig);
    easort_kernel<<<(NE * 16) / 256, 256, 0, stream>>>(edge_attr, eorig, eas);

    const int nDual = MT1 * 4 + (ECH / GBM) * 2;   // 628 + 2500 = 3128
    const dim3 gPe(ECH / GBM, 2);                  // 1250 x 2

    for (int s = 0; s < NSTEPS; s++) {
        const unsigned short* wb = wbuf + (size_t)s * WSTEP;
        const unsigned short* WabT = wb;            // [512][256]: Wa^T rows 0-255, Wb^T rows 256-511
        const unsigned short* WcT  = wb + 131072;   // [256][64]
        const unsigned short* eW2T = wb + 147456;   // [256][256]
        const unsigned short* nW1T = wb + 212992;   // [512][512]
        const unsigned short* nW2T = wb + 475136;   // [256][512]
        const float* eb1s = eb1 + (size_t)s * HH;
        const float* eb2s = eb2 + (size_t)s * HH;
        const float* nb1s = nb1 + (size_t)s * 512;
        const float* nb2s = nb2 + (size_t)s * HH;

        // hn = bf16(LN(h))
        ln_kernel<<<NN / 4, 256, 0, stream>>>(h, nn_g + s * HH, nn_b + s * HH, hn, NN);
        // Pab = bf16(hn @ [Wa|Wb])  AND  Pe(c0) = eas_c0 @ Wc + eb1  -- one overlapped launch
        dual_kernel<<<nDual, 256, 0, stream>>>(hn, WabT, Pab, eas, WcT, eb1s, Pe);
        agg_kernel<true><<<(NN + 3) / 4, 256, 0, stream>>>(Pab, Pe, esrc, rowptr, u, 0, ECH);
        // Pe(c1), then agg chunk 1 (RMW)
        mgemm<0, 3, true, 128><<<gPe, 256, 0, stream>>>(eas + (size_t)ECH * EDK, nullptr, EDK, WcT, eb1s, nullptr, Pe, ECH, HH, EDK);
        agg_kernel<false><<<(NN + 3) / 4, 256, 0, stream>>>(Pab, Pe, esrc, rowptr, u, ECH, NE);
        // aggp = (u @ eW2 + cnt*eb2)/max(cnt,1)  [fp32] ; aggb = bf16(LN(aggp))
        mgemm<2, 3, false, 64><<<dim3(MT1, 4), 256, 0, stream>>>(u, nullptr, HH, eW2T, eb2s, cnt, aggp, NN, HH, HH);
        ln_kernel<<<NN / 4, 256, 0, stream>>>(aggp, mn_g + s * HH, mn_b + s * HH, aggb, NN);
        // zb = bf16(silu([hn, aggb] @ nW1 + nb1))
        mgemm<1, 4, true, 64><<<dim3(MT1, 8), 256, 0, stream>>>(hn, aggb, HH, nW1T, nb1s, nullptr, zb, NN, 512, 512);
        // h += zb @ nW2 + nb2
        mgemm<3, 3, false, 64><<<dim3(MT1, 4), 256, 0, stream>>>(zb, nullptr, 512, nW2T, nb2s, nullptr, h, NN, HH, 512);
    }
}